// Round 9
// baseline (559.240 us; speedup 1.0000x reference)
//
#include <hip/hip_runtime.h>
#include <hip/hip_cooperative_groups.h>
#include <stdint.h>

#define Hh 512
#define Ww 768
#define HW (Hh*Ww)
#define Bb 4
#define Cc 129
#define DESC 128
#define KK 2048
#define NBINS 4096
#define CAP 24                    // max survivors per 60-wide chunk (no-tie bound is 20)
#define CHUNKS 13
#define NTASK (Bb*Hh*CHUNKS)      // 26624
#define TPB (Hh*CHUNKS)           // 6656 tasks per batch
#define SORT_CAP 4096
#define GRIDB 512

namespace cg = cooperative_groups;

__global__ __launch_bounds__(256, 2) void disk_fused(
    const float* __restrict__ unet, float* __restrict__ out,
    uint64_t* __restrict__ cand,   // [CAP][NTASK] transposed slots
    uint32_t* __restrict__ counts, // [NTASK] plain-stored every call
    uint32_t* __restrict__ hist,   // [Bb][NBINS]
    uint32_t* __restrict__ rnk_g,  // [Bb][SORT_CAP]
    uint64_t* __restrict__ kps)    // [Bb*KK] y-sorted (rank<<32)|idx
{
    __shared__ uint32_t S[NBINS + 8];
    __shared__ uint64_t keys[SORT_CAP];
    __shared__ uint32_t ybins[Hh];
    __shared__ uint32_t scan[256];
    __shared__ uint32_t sThr;

    cg::grid_group grid = cg::this_grid();
    int tid = threadIdx.x;
    int wid = tid >> 6, lane = tid & 63;
    int gw = blockIdx.x * 4 + wid;          // 0..2047 == b*512 + y
    int b1 = gw >> 9, y = gw & (Hh - 1);

    // ---------------- P1: zero hist + separable 5x5 NMS (atomic-free emit) ----------------
    if (blockIdx.x < 64) hist[blockIdx.x * 256 + tid] = 0u;   // 64*256 == Bb*NBINS

    {
        const float* hb = unet + ((size_t)(b1 * Cc + DESC)) * HW;
        int y0 = max(y-2,0), y1 = max(y-1,0), y3 = min(y+1,Hh-1), y4 = min(y+2,Hh-1);
        const float* p0 = hb + (size_t)y0*Ww; const float* p1 = hb + (size_t)y1*Ww;
        const float* p2 = hb + (size_t)y *Ww; const float* p3 = hb + (size_t)y3*Ww;
        const float* p4 = hb + (size_t)y4*Ww;
        for (int chunk = 0; chunk < CHUNKS; ++chunk) {
            int x = chunk*60 + lane - 2;
            int xc = min(max(x,0), Ww-1);
            float r0=p0[xc], r1=p1[xc], r2=p2[xc], r3=p3[xc], r4=p4[xc];
            float cm = fmaxf(fmaxf(fmaxf(r0,r1),fmaxf(r3,r4)),r2);
            float m1 = fmaxf(__shfl(cm,lane-1), __shfl(cm,lane+1));
            float m2 = fmaxf(__shfl(cm,lane-2), __shfl(cm,lane+2));
            float hm = fmaxf(cm, fmaxf(m1,m2));
            bool surv = (lane>=2) && (lane<=61) && (x<Ww) && (r2>0.0f) && (r2>=hm);
            uint64_t ball = __ballot(surv);
            int task = gw*CHUNKS + chunk;
            if (surv) {
                uint32_t p = (uint32_t)__popcll(ball & ((1ull<<lane)-1ull));
                if (p < CAP)
                    cand[(size_t)p*NTASK + task] =
                        ((uint64_t)__float_as_uint(r2)<<32) | (uint32_t)(~(uint32_t)(y*Ww+x));
            }
            if (lane == 0) counts[task] = min((uint32_t)__popcll(ball), (uint32_t)CAP);
        }
    }

    __threadfence();
    grid.sync();

    // ---------------- P2a: per-batch histogram (16 blocks, 4 per batch) ----------------
    if (blockIdx.x < 16) {
        int b = blockIdx.x >> 2, part = blockIdx.x & 3;
        int s0 = b*TPB + part*(TPB/4);
        for (int s = s0 + tid; s < s0 + TPB/4; s += 256) {
            uint32_t c = counts[s];
            for (uint32_t j = 0; j < c; ++j) {
                uint64_t key = cand[(size_t)j*NTASK + s];
                atomicAdd(&hist[b*NBINS + (uint32_t)(key>>51)], 1u);
            }
        }
    }
    __threadfence();
    grid.sync();

    // ---------------- P2b: per-batch top-k rank + emit + y-sort (4 blocks) ----------------
    if (blockIdx.x < Bb) {
        int b = blockIdx.x;
        uint32_t h[16]; uint32_t tot = 0;
        #pragma unroll
        for (int k = 0; k < 16; ++k) { h[k] = hist[b*NBINS + tid*16 + k]; tot += h[k]; }
        scan[tid] = tot;
        if (tid == 0) sThr = 0u;
        if (tid == 255) {
            for (int k = 0; k < 8; ++k) S[NBINS + k] = 0u;
        }
        __syncthreads();
        for (int off = 1; off < 256; off <<= 1) {
            uint32_t v = scan[tid] + ((tid+off<256)? scan[tid+off] : 0u);
            __syncthreads(); scan[tid] = v; __syncthreads();
        }
        {
            uint32_t next = (tid<255)? scan[tid+1] : 0u;    // suffix from bin 16(t+1)
            #pragma unroll
            for (int k = 15; k >= 0; --k) {
                uint32_t cur = next + h[k];
                if (cur >= KK && next < KK) sThr = (uint32_t)(tid*16+k);
                S[tid*16+k] = cur;
                next = cur;
            }
        }
        __syncthreads();
        uint32_t thr = sThr;
        uint32_t m = S[thr]; if (m > SORT_CAP) m = SORT_CAP;

        // counting-scatter into keys (bin-grouped); post-scatter S[b+1]=S_old[b]
        for (int s = b*TPB + tid; s < (b+1)*TPB; s += 256) {
            uint32_t c = counts[s];
            for (uint32_t j = 0; j < c; ++j) {
                uint64_t key = cand[(size_t)j*NTASK + s];
                uint32_t bin = (uint32_t)(key>>51);
                if (bin >= thr) {
                    uint32_t p = atomicAdd(&S[bin+1], 1u);
                    if (p < SORT_CAP) keys[p] = key;
                }
            }
        }
        __syncthreads();

        float* out_kp = out;
        float* out_sc = out + (size_t)Bb*KK*2;
        for (uint32_t p = tid; p < m; p += 256) {
            uint64_t key = keys[p];
            uint32_t bin = (uint32_t)(key>>51);
            uint32_t base = S[bin+2];            // = S_old[bin+1]
            uint32_t end  = S[bin+1];            // = S_old[bin]
            if (end > m) end = m;
            uint32_t rank = base;
            for (uint32_t q = base; q < end; ++q)
                rank += (keys[q] > key) ? 1u : 0u;
            rnk_g[b*SORT_CAP + p] = rank;
            if (rank < KK) {
                uint32_t idx = ~((uint32_t)key);
                uint32_t yy = idx / Ww, xx = idx - yy*Ww;
                size_t o = (size_t)b*KK + rank;
                out_kp[o*2+0] = (float)xx;
                out_kp[o*2+1] = (float)yy;
                out_sc[o] = __uint_as_float((uint32_t)(key>>32));
            }
        }
        // y-sort winners for gather locality
        for (int i = tid; i < Hh; i += 256) ybins[i] = 0u;
        __syncthreads();
        for (uint32_t p = tid; p < m; p += 256)
            if (rnk_g[b*SORT_CAP + p] < KK)
                atomicAdd(&ybins[(~((uint32_t)keys[p])) / Ww], 1u);
        __syncthreads();
        {
            uint32_t a = ybins[2*tid], b2 = ybins[2*tid+1];
            uint32_t t2 = a + b2;
            scan[tid] = t2;
            __syncthreads();
            for (int off = 1; off < 256; off <<= 1) {
                uint32_t v = scan[tid] + ((tid>=off)? scan[tid-off] : 0u);
                __syncthreads(); scan[tid] = v; __syncthreads();
            }
            uint32_t excl = scan[tid] - t2;
            ybins[2*tid]   = excl;
            ybins[2*tid+1] = excl + a;
        }
        __syncthreads();
        for (uint32_t p = tid; p < m; p += 256) {
            uint32_t rank = rnk_g[b*SORT_CAP + p];
            if (rank < KK) {
                uint32_t idx = ~((uint32_t)keys[p]);
                uint32_t j = atomicAdd(&ybins[idx / Ww], 1u);
                kps[(size_t)b*KK + j] = ((uint64_t)rank << 32) | idx;
            }
        }
    }
    __threadfence();
    grid.sync();

    // ---------------- P3: descriptor gather + L2 normalize ----------------
    {
        float* out_desc = out + (size_t)Bb*KK*2 + (size_t)Bb*KK;
        for (int r = 0; r < 4; ++r) {
            int kp = r*2048 + gw;                // batch == r, j == gw (y-sorted)
            uint64_t e = kps[kp];
            uint32_t idx  = (uint32_t)e;
            uint32_t rank = (uint32_t)(e >> 32);
            float v0 = 0.0f, v1 = 0.0f;
            if (idx < (uint32_t)HW) {
                const float* base = unet + (size_t)r*Cc*HW + idx;
                v0 = base[(size_t)lane*HW];
                v1 = base[(size_t)(lane+64)*HW];
            }
            float s = v0*v0 + v1*v1;
            #pragma unroll
            for (int off = 32; off > 0; off >>= 1) s += __shfl_xor(s, off);
            float rn = 1.0f / fmaxf(sqrtf(s), 1e-12f);
            if (rank < KK) {
                float* o = out_desc + ((size_t)r*KK + rank)*DESC;
                o[lane]      = v0*rn;
                o[lane+64]   = v1*rn;
            }
        }
    }
}

extern "C" void kernel_launch(void* const* d_in, const int* in_sizes, int n_in,
                              void* d_out, int out_size, void* d_ws, size_t ws_size,
                              hipStream_t stream) {
    const float* unet = (const float*)d_in[0];
    float* out = (float*)d_out;
    uint8_t* ws = (uint8_t*)d_ws;

    uint64_t* cand   = (uint64_t*)(ws);                       // 24*26624*8 = 5,111,808
    uint32_t* counts = (uint32_t*)(ws + 5111808);             // 106,496
    uint32_t* hist   = (uint32_t*)(ws + 5218304);             // 65,536
    uint32_t* rnk_g  = (uint32_t*)(ws + 5283840);             // 65,536
    uint64_t* kps    = (uint64_t*)(ws + 5349376);             // 65,536

    void* args[] = { (void*)&unet, (void*)&out, (void*)&cand,
                     (void*)&counts, (void*)&hist, (void*)&rnk_g, (void*)&kps };
    (void)hipLaunchCooperativeKernel((const void*)disk_fused, dim3(GRIDB), dim3(256),
                                     args, 0, stream);
}

// Round 10
// 250.527 us; speedup vs baseline: 2.2323x; 2.2323x over previous
//
#include <hip/hip_runtime.h>
#include <stdint.h>

#define Hh 512
#define Ww 768
#define HW (Hh*Ww)
#define Bb 4
#define Cc 129
#define DESC 128
#define KK 2048
#define NBINS 4096
#define CAP 24                    // max survivors per 60-wide chunk
#define CHUNKS 13
#define NTASK (Bb*Hh*CHUNKS)      // 26624 row-chunk tasks
#define TASKS_B (Hh*CHUNKS)       // 6656 per batch
#define SORT_CAP 4096
#define GRIDB 256
#define NTHR 512

__global__ void init_bar(uint32_t* bar) { if (threadIdx.x < 8) bar[threadIdx.x] = 0u; }

// Hand-rolled grid barrier: 1 atomic arrival per block, relaxed agent-scope poll,
// release/acquire fences (L2 wb/inv) once in thread 0. Counters zeroed by init_bar
// each call, so plain monotonic count to GRIDB is safe.
__device__ __forceinline__ void gbar(uint32_t* ctr) {
    __syncthreads();
    if (threadIdx.x == 0) {
        __threadfence();  // release: make this XCD's L2 dirty lines device-visible
        __hip_atomic_fetch_add(ctr, 1u, __ATOMIC_ACQ_REL, __HIP_MEMORY_SCOPE_AGENT);
        while (__hip_atomic_load(ctr, __ATOMIC_RELAXED, __HIP_MEMORY_SCOPE_AGENT) < GRIDB)
            __builtin_amdgcn_s_sleep(4);
        __threadfence();  // acquire: invalidate stale L1/L2 before reads
    }
    __syncthreads();
}

__global__ __launch_bounds__(NTHR, 1) void disk_fused(
    const float* __restrict__ unet, float* __restrict__ out,
    uint64_t* __restrict__ cand,   // [CAP][NTASK] transposed slots
    uint32_t* __restrict__ counts, // [NTASK] plain-stored every call
    uint32_t* __restrict__ bar,    // barrier counters (zeroed by init_bar)
    uint32_t* __restrict__ rnk_g,  // [Bb][SORT_CAP]
    uint64_t* __restrict__ kps)    // [Bb*KK] y-sorted (rank<<32)|idx
{
    __shared__ uint32_t S[NBINS + 8];
    __shared__ uint64_t keys[SORT_CAP];
    __shared__ uint32_t ybins[Hh];
    __shared__ uint32_t scan[NTHR];
    __shared__ uint32_t sThr;

    int tid = threadIdx.x;
    int wid = tid >> 6, lane = tid & 63;
    int gw = blockIdx.x * 8 + wid;          // 0..2047 == b*512 + y
    int b1 = gw >> 9, y = gw & (Hh - 1);

    // ---------------- P1: separable 5x5 NMS, atomic-free emit ----------------
    {
        const float* hb = unet + ((size_t)(b1 * Cc + DESC)) * HW;
        int y0 = max(y-2,0), y1 = max(y-1,0), y3 = min(y+1,Hh-1), y4 = min(y+2,Hh-1);
        const float* p0 = hb + (size_t)y0*Ww; const float* p1 = hb + (size_t)y1*Ww;
        const float* p2 = hb + (size_t)y *Ww; const float* p3 = hb + (size_t)y3*Ww;
        const float* p4 = hb + (size_t)y4*Ww;
        for (int chunk = 0; chunk < CHUNKS; ++chunk) {
            int x = chunk*60 + lane - 2;
            int xc = min(max(x,0), Ww-1);
            float r0=p0[xc], r1=p1[xc], r2=p2[xc], r3=p3[xc], r4=p4[xc];
            float cm = fmaxf(fmaxf(fmaxf(r0,r1),fmaxf(r3,r4)),r2);
            float m1 = fmaxf(__shfl(cm,lane-1), __shfl(cm,lane+1));
            float m2 = fmaxf(__shfl(cm,lane-2), __shfl(cm,lane+2));
            float hm = fmaxf(cm, fmaxf(m1,m2));
            bool surv = (lane>=2) && (lane<=61) && (x<Ww) && (r2>0.0f) && (r2>=hm);
            uint64_t ball = __ballot(surv);
            int task = gw*CHUNKS + chunk;
            if (surv) {
                uint32_t p = (uint32_t)__popcll(ball & ((1ull<<lane)-1ull));
                if (p < CAP)
                    cand[(size_t)p*NTASK + task] =
                        ((uint64_t)__float_as_uint(r2)<<32) | (uint32_t)(~(uint32_t)(y*Ww+x));
            }
            if (lane == 0) counts[task] = min((uint32_t)__popcll(ball), (uint32_t)CAP);
        }
    }

    gbar(&bar[0]);

    // ---------------- P2: per-batch topk rank + emit + y-sort (4 blocks) ----------------
    if (blockIdx.x < Bb) {
        int b = blockIdx.x;
        for (int i = tid; i < NBINS + 8; i += NTHR) S[i] = 0u;
        if (tid == 0) sThr = 0u;
        __syncthreads();
        const int s0 = b * TASKS_B;
        for (int s = s0 + tid; s < s0 + TASKS_B; s += NTHR) {
            uint32_t c = counts[s];
            for (uint32_t j = 0; j < c; ++j)
                atomicAdd(&S[(uint32_t)(cand[(size_t)j*NTASK + s] >> 51)], 1u);
        }
        __syncthreads();
        // suffix scan over 4096 bins, thread owns 8
        uint32_t h[8]; uint32_t tot = 0;
        #pragma unroll
        for (int k = 0; k < 8; ++k) { h[k] = S[tid*8+k]; tot += h[k]; }
        scan[tid] = tot;
        __syncthreads();
        for (int off = 1; off < NTHR; off <<= 1) {
            uint32_t v = scan[tid] + ((tid+off<NTHR)? scan[tid+off] : 0u);
            __syncthreads(); scan[tid] = v; __syncthreads();
        }
        {
            uint32_t next = (tid<NTHR-1)? scan[tid+1] : 0u;
            #pragma unroll
            for (int k = 7; k >= 0; --k) {
                uint32_t cur = next + h[k];
                if (cur >= KK && next < KK) sThr = (uint32_t)(tid*8+k);
                S[tid*8+k] = cur;
                next = cur;
            }
        }
        __syncthreads();
        uint32_t thr = sThr;
        uint32_t m = S[thr]; if (m > SORT_CAP) m = SORT_CAP;

        // counting-scatter (bin-grouped); post-scatter S[i+1] = S_old[i]
        for (int s = s0 + tid; s < s0 + TASKS_B; s += NTHR) {
            uint32_t c = counts[s];
            for (uint32_t j = 0; j < c; ++j) {
                uint64_t key = cand[(size_t)j*NTASK + s];
                uint32_t bin = (uint32_t)(key>>51);
                if (bin >= thr) {
                    uint32_t p = atomicAdd(&S[bin+1], 1u);
                    if (p < SORT_CAP) keys[p] = key;
                }
            }
        }
        __syncthreads();

        float* out_kp = out;
        float* out_sc = out + (size_t)Bb*KK*2;
        for (uint32_t p = tid; p < m; p += NTHR) {
            uint64_t key = keys[p];
            uint32_t bin = (uint32_t)(key>>51);
            uint32_t base = S[bin+2];            // = S_old[bin+1]
            uint32_t end  = S[bin+1];            // = S_old[bin]
            if (end > m) end = m;
            uint32_t rank = base;
            for (uint32_t q = base; q < end; ++q)
                rank += (keys[q] > key) ? 1u : 0u;
            rnk_g[b*SORT_CAP + p] = rank;
            if (rank < KK) {
                uint32_t idx = ~((uint32_t)key);
                uint32_t yy = idx / Ww, xx = idx - yy*Ww;
                size_t o = (size_t)b*KK + rank;
                out_kp[o*2+0] = (float)xx;
                out_kp[o*2+1] = (float)yy;
                out_sc[o] = __uint_as_float((uint32_t)(key>>32));
            }
        }
        // y-sort winners for gather locality
        ybins[tid] = 0u;
        __syncthreads();
        for (uint32_t p = tid; p < m; p += NTHR)
            if (rnk_g[b*SORT_CAP + p] < KK)
                atomicAdd(&ybins[(~((uint32_t)keys[p])) / Ww], 1u);
        __syncthreads();
        {
            uint32_t mine = ybins[tid];
            scan[tid] = mine;
            __syncthreads();
            for (int off = 1; off < NTHR; off <<= 1) {
                uint32_t v = scan[tid] + ((tid>=off)? scan[tid-off] : 0u);
                __syncthreads(); scan[tid] = v; __syncthreads();
            }
            ybins[tid] = scan[tid] - mine;   // exclusive base; reused as cursor
        }
        __syncthreads();
        for (uint32_t p = tid; p < m; p += NTHR) {
            uint32_t rank = rnk_g[b*SORT_CAP + p];
            if (rank < KK) {
                uint32_t idx = ~((uint32_t)keys[p]);
                uint32_t j = atomicAdd(&ybins[idx / Ww], 1u);
                kps[(size_t)b*KK + j] = ((uint64_t)rank << 32) | idx;
            }
        }
    }

    gbar(&bar[1]);

    // ---------------- P3: descriptor gather + L2 normalize (4 kp in flight) ----------------
    {
        float* out_desc = out + (size_t)Bb*KK*2 + (size_t)Bb*KK;
        float v0[4], v1[4];
        uint32_t rk[4];
        #pragma unroll
        for (int r = 0; r < 4; ++r) {
            uint64_t e = kps[(size_t)r*KK + gw];      // batch r, y-sorted slot gw
            uint32_t idx = (uint32_t)e;
            rk[r] = (uint32_t)(e >> 32);
            const float* base = unet + (size_t)r*Cc*HW + idx;
            v0[r] = base[(size_t)lane*HW];
            v1[r] = base[(size_t)(lane+64)*HW];
        }
        #pragma unroll
        for (int r = 0; r < 4; ++r) {
            float s = v0[r]*v0[r] + v1[r]*v1[r];
            #pragma unroll
            for (int off = 32; off > 0; off >>= 1) s += __shfl_xor(s, off);
            float rn = 1.0f / fmaxf(sqrtf(s), 1e-12f);
            float* o = out_desc + ((size_t)r*KK + rk[r])*DESC;
            o[lane]      = v0[r]*rn;
            o[lane+64]   = v1[r]*rn;
        }
    }
}

extern "C" void kernel_launch(void* const* d_in, const int* in_sizes, int n_in,
                              void* d_out, int out_size, void* d_ws, size_t ws_size,
                              hipStream_t stream) {
    const float* unet = (const float*)d_in[0];
    float* out = (float*)d_out;
    uint8_t* ws = (uint8_t*)d_ws;

    uint64_t* cand   = (uint64_t*)(ws);                       // 24*26624*8 = 5,111,808
    uint32_t* counts = (uint32_t*)(ws + 5111808);             // 106,496
    uint32_t* bar    = (uint32_t*)(ws + 5218304);             // 64
    uint64_t* kps    = (uint64_t*)(ws + 5218368);             // 65,536
    uint32_t* rnk_g  = (uint32_t*)(ws + 5283904);             // 65,536

    init_bar<<<1, 64, 0, stream>>>(bar);

    void* args[] = { (void*)&unet, (void*)&out, (void*)&cand,
                     (void*)&counts, (void*)&bar, (void*)&rnk_g, (void*)&kps };
    (void)hipLaunchCooperativeKernel((const void*)disk_fused, dim3(GRIDB), dim3(NTHR),
                                     args, 0, stream);
}

// Round 11
// 129.209 us; speedup vs baseline: 4.3282x; 1.9389x over previous
//
#include <hip/hip_runtime.h>
#include <stdint.h>

#define Hh 512
#define Ww 768
#define HW (Hh*Ww)
#define Bb 4
#define Cc 129
#define DESC 128
#define KK 2048
#define NBINS 4096
#define CAP 24                    // max survivors per 60-wide chunk (no-tie bound is 20)
#define CHUNKS 13
#define NTASK (Bb*Hh*CHUNKS)      // 26624 row-chunk tasks
#define TASKS_B (Hh*CHUNKS)       // 6656 per batch
#define SORT_CAP 4096

// Separable 5x5 NMS, fully atomic-free emit: each row-chunk task owns CAP
// transposed slots cand[j][task]; counts[task] plain-stored every call
// (no zeroing kernel needed, poison-safe).
__global__ __launch_bounds__(256) void nms_collect(const float* __restrict__ unet,
                                                   uint64_t* __restrict__ cand,
                                                   uint32_t* __restrict__ counts) {
    int wid = threadIdx.x >> 6;
    int lane = threadIdx.x & 63;
    int w = blockIdx.x * 4 + wid;          // task id, [0, NTASK)
    int chunk = w % CHUNKS;
    int t = w / CHUNKS;
    int y = t & (Hh - 1);
    int b = t >> 9;
    int x = chunk * 60 + lane - 2;
    int xc = min(max(x, 0), Ww - 1);
    const float* hb = unet + ((size_t)(b * Cc + DESC)) * HW;

    int y0 = max(y - 2, 0), y1 = max(y - 1, 0);
    int y3 = min(y + 1, Hh - 1), y4 = min(y + 2, Hh - 1);
    float r0 = hb[y0 * Ww + xc];
    float r1 = hb[y1 * Ww + xc];
    float r2 = hb[y  * Ww + xc];
    float r3 = hb[y3 * Ww + xc];
    float r4 = hb[y4 * Ww + xc];
    float cm = fmaxf(fmaxf(fmaxf(r0, r1), fmaxf(r3, r4)), r2);
    float m1 = fmaxf(__shfl(cm, lane - 1), __shfl(cm, lane + 1));
    float m2 = fmaxf(__shfl(cm, lane - 2), __shfl(cm, lane + 2));
    float hm = fmaxf(cm, fmaxf(m1, m2));
    bool surv = (lane >= 2) && (lane <= 61) && (x < Ww) && (r2 > 0.0f) && (r2 >= hm);

    uint64_t ball = __ballot(surv);
    if (surv) {
        uint32_t p = (uint32_t)__popcll(ball & ((1ull << lane) - 1ull));
        if (p < CAP)
            cand[(size_t)p * NTASK + w] =
                ((uint64_t)__float_as_uint(r2) << 32) | (uint32_t)(~(uint32_t)(y * Ww + x));
    }
    if (lane == 0) counts[w] = min((uint32_t)__popcll(ball), (uint32_t)CAP);
}

// Per-batch rank-by-counting top-k over per-task counted lists (coalesced in task
// for fixed slot j), then counting-sort winners by row y for gather locality.
__global__ __launch_bounds__(1024) void topk_rank(const uint64_t* __restrict__ cand,
                                                  const uint32_t* __restrict__ counts,
                                                  float* __restrict__ out,
                                                  uint64_t* __restrict__ kps) {
    __shared__ uint32_t S[NBINS + 8];
    __shared__ uint32_t scan[1024];
    __shared__ uint64_t keys[SORT_CAP];
    __shared__ uint32_t rnk[SORT_CAP];
    __shared__ uint32_t ybins[Hh];
    __shared__ uint32_t sThr;
    int b = blockIdx.x;
    int tid = threadIdx.x;
    const int s0 = b * TASKS_B;

    for (int i = tid; i < NBINS + 8; i += 1024) S[i] = 0u;
    if (tid == 0) sThr = 0u;
    __syncthreads();

    for (int s = s0 + tid; s < s0 + TASKS_B; s += 1024) {
        uint32_t c = counts[s];
        for (uint32_t j = 0; j < c; ++j)
            atomicAdd(&S[(uint32_t)(cand[(size_t)j * NTASK + s] >> 51)], 1u);
    }
    __syncthreads();

    // hist -> per-bin suffix counts (in place); thread t owns bins [4t,4t+4)
    uint32_t h0 = S[4*tid], h1 = S[4*tid+1], h2 = S[4*tid+2], h3 = S[4*tid+3];
    scan[tid] = h0 + h1 + h2 + h3;
    __syncthreads();
    #pragma unroll
    for (int off = 1; off < 1024; off <<= 1) {
        uint32_t v = scan[tid] + ((tid + off < 1024) ? scan[tid + off] : 0u);
        __syncthreads();
        scan[tid] = v;
        __syncthreads();
    }
    {
        uint32_t sfx4 = (tid < 1023) ? scan[tid + 1] : 0u;
        uint32_t S3 = h3 + sfx4, S2 = h2 + S3, S1 = h1 + S2, S0 = h0 + S1;
        S[4*tid] = S0; S[4*tid+1] = S1; S[4*tid+2] = S2; S[4*tid+3] = S3;
        if (S3 >= KK && sfx4 < KK) sThr = (uint32_t)(4*tid + 3);
        if (S2 >= KK && S3   < KK) sThr = (uint32_t)(4*tid + 2);
        if (S1 >= KK && S2   < KK) sThr = (uint32_t)(4*tid + 1);
        if (S0 >= KK && S1   < KK) sThr = (uint32_t)(4*tid + 0);
    }
    __syncthreads();

    uint32_t thr = sThr;
    uint32_t m = S[thr];
    if (m > SORT_CAP) m = SORT_CAP;

    // counting-scatter (bin-grouped); post-scatter S[i+1] = S_old[i]
    for (int s = s0 + tid; s < s0 + TASKS_B; s += 1024) {
        uint32_t c = counts[s];
        for (uint32_t j = 0; j < c; ++j) {
            uint64_t key = cand[(size_t)j * NTASK + s];
            uint32_t bin = (uint32_t)(key >> 51);
            if (bin >= thr) {
                uint32_t p = atomicAdd(&S[bin + 1], 1u);
                if (p < SORT_CAP) keys[p] = key;
            }
        }
    }
    __syncthreads();

    // rank = segment base + within-bin greater-count; emit coords/scores
    float* out_kp = out;                      // (B,K,2)
    float* out_sc = out + (size_t)Bb * KK * 2;
    for (uint32_t p = tid; p < m; p += 1024) {
        uint64_t key = keys[p];
        uint32_t bin = (uint32_t)(key >> 51);
        uint32_t base = S[bin + 2];           // = S_old[bin+1]
        uint32_t end  = S[bin + 1];           // = S_old[bin]
        if (end > m) end = m;
        uint32_t rank = base;
        for (uint32_t q = base; q < end; ++q)
            rank += (keys[q] > key) ? 1u : 0u;
        rnk[p] = rank;
        if (rank < KK) {
            uint32_t idx = ~((uint32_t)key);
            uint32_t yy = idx / Ww, xx = idx - yy * Ww;
            size_t o = (size_t)b * KK + rank;
            out_kp[o * 2 + 0] = (float)xx;
            out_kp[o * 2 + 1] = (float)yy;
            out_sc[o] = __uint_as_float((uint32_t)(key >> 32));
        }
    }
    __syncthreads();

    // y-histogram of winners
    for (int i = tid; i < Hh; i += 1024) ybins[i] = 0u;
    __syncthreads();
    for (uint32_t p = tid; p < m; p += 1024)
        if (rnk[p] < KK)
            atomicAdd(&ybins[(~((uint32_t)keys[p])) / Ww], 1u);
    __syncthreads();

    // exclusive scan of ybins
    uint32_t hv = 0;
    if (tid < Hh) { hv = ybins[tid]; scan[tid] = hv; }
    __syncthreads();
    for (int off = 1; off < Hh; off <<= 1) {
        uint32_t v2 = 0;
        if (tid < Hh) v2 = scan[tid] + ((tid >= off) ? scan[tid - off] : 0u);
        __syncthreads();
        if (tid < Hh) scan[tid] = v2;
        __syncthreads();
    }
    if (tid < Hh) ybins[tid] = scan[tid] - hv;   // exclusive base; reused as cursor
    __syncthreads();

    // scatter winners grouped by y: kps[b*KK + j] = (rank<<32)|idx
    for (uint32_t p = tid; p < m; p += 1024) {
        uint32_t rank = rnk[p];
        if (rank < KK) {
            uint32_t idx = ~((uint32_t)keys[p]);
            uint32_t j = atomicAdd(&ybins[idx / Ww], 1u);
            kps[(size_t)b * KK + j] = ((uint64_t)rank << 32) | idx;
        }
    }
}

// 4 keypoints per 256-thread block (one per wave), in y-sorted order for DRAM locality.
__global__ __launch_bounds__(256) void gather_desc(const float* __restrict__ unet,
                                                   const uint64_t* __restrict__ kps,
                                                   float* __restrict__ out_desc) {
    int kp = blockIdx.x * 4 + (threadIdx.x >> 6);
    int lane = threadIdx.x & 63;
    int b = kp >> 11;
    uint64_t e = kps[kp];
    uint32_t idx  = (uint32_t)e;
    uint32_t rank = (uint32_t)(e >> 32);
    float v0 = 0.0f, v1 = 0.0f;
    if (idx < (uint32_t)HW) {
        const float* base = unet + (size_t)b * Cc * HW + idx;
        v0 = base[(size_t)lane * HW];
        v1 = base[(size_t)(lane + 64) * HW];
    }
    float s = v0 * v0 + v1 * v1;
    #pragma unroll
    for (int off = 32; off > 0; off >>= 1) s += __shfl_xor(s, off);
    float rn = 1.0f / fmaxf(sqrtf(s), 1e-12f);
    if (rank < KK) {
        float* o = out_desc + ((size_t)b * KK + rank) * DESC;
        o[lane]      = v0 * rn;
        o[lane + 64] = v1 * rn;
    }
}

extern "C" void kernel_launch(void* const* d_in, const int* in_sizes, int n_in,
                              void* d_out, int out_size, void* d_ws, size_t ws_size,
                              hipStream_t stream) {
    const float* unet = (const float*)d_in[0];
    float* out = (float*)d_out;
    uint8_t* ws = (uint8_t*)d_ws;

    uint64_t* cand   = (uint64_t*)(ws);                       // 24*26624*8 = 5,111,808
    uint32_t* counts = (uint32_t*)(ws + 5111808);             // 106,496
    uint64_t* kps    = (uint64_t*)(ws + 5218304);             // 65,536

    float* out_desc = out + (size_t)Bb * KK * 2 + (size_t)Bb * KK;

    nms_collect<<<NTASK / 4, 256, 0, stream>>>(unet, cand, counts);
    topk_rank<<<Bb, 1024, 0, stream>>>(cand, counts, out, kps);
    gather_desc<<<Bb * KK / 4, 256, 0, stream>>>(unet, kps, out_desc);
}

// Round 12
// 126.051 us; speedup vs baseline: 4.4366x; 1.0251x over previous
//
#include <hip/hip_runtime.h>
#include <stdint.h>

#define Hh 512
#define Ww 768
#define HW (Hh*Ww)
#define Bb 4
#define Cc 129
#define DESC 128
#define KK 2048
#define NBINS 4096
#define CAP 24                    // max survivors per 60-wide chunk (no-tie bound is 20)
#define CHUNKS 13
#define NTASK (Bb*Hh*CHUNKS)      // 26624 row-chunk tasks
#define TASKS_B (Hh*CHUNKS)       // 6656 per batch
#define SORT_CAP 4096

// Separable 5x5 NMS, fully atomic-free emit: each row-chunk task owns CAP
// transposed slots cand[j][task]; counts[task] plain-stored every call.
__global__ __launch_bounds__(256) void nms_collect(const float* __restrict__ unet,
                                                   uint64_t* __restrict__ cand,
                                                   uint32_t* __restrict__ counts) {
    int wid = threadIdx.x >> 6;
    int lane = threadIdx.x & 63;
    int w = blockIdx.x * 4 + wid;          // task id, [0, NTASK)
    int chunk = w % CHUNKS;
    int t = w / CHUNKS;
    int y = t & (Hh - 1);
    int b = t >> 9;
    int x = chunk * 60 + lane - 2;
    int xc = min(max(x, 0), Ww - 1);
    const float* hb = unet + ((size_t)(b * Cc + DESC)) * HW;

    int y0 = max(y - 2, 0), y1 = max(y - 1, 0);
    int y3 = min(y + 1, Hh - 1), y4 = min(y + 2, Hh - 1);
    float r0 = hb[y0 * Ww + xc];
    float r1 = hb[y1 * Ww + xc];
    float r2 = hb[y  * Ww + xc];
    float r3 = hb[y3 * Ww + xc];
    float r4 = hb[y4 * Ww + xc];
    float cm = fmaxf(fmaxf(fmaxf(r0, r1), fmaxf(r3, r4)), r2);
    float m1 = fmaxf(__shfl(cm, lane - 1), __shfl(cm, lane + 1));
    float m2 = fmaxf(__shfl(cm, lane - 2), __shfl(cm, lane + 2));
    float hm = fmaxf(cm, fmaxf(m1, m2));
    bool surv = (lane >= 2) && (lane <= 61) && (x < Ww) && (r2 > 0.0f) && (r2 >= hm);

    uint64_t ball = __ballot(surv);
    if (surv) {
        uint32_t p = (uint32_t)__popcll(ball & ((1ull << lane) - 1ull));
        if (p < CAP)
            cand[(size_t)p * NTASK + w] =
                ((uint64_t)__float_as_uint(r2) << 32) | (uint32_t)(~(uint32_t)(y * Ww + x));
    }
    if (lane == 0) counts[w] = min((uint32_t)__popcll(ball), (uint32_t)CAP);
}

// Per-batch rank-by-counting top-k. Suffix scan via wave shuffles (3 barriers).
// Emits coords/scores at rank and kp_idx[b*KK+rank] = pixel idx. No sort, no y-sort.
__global__ __launch_bounds__(1024) void topk_rank(const uint64_t* __restrict__ cand,
                                                  const uint32_t* __restrict__ counts,
                                                  float* __restrict__ out,
                                                  uint32_t* __restrict__ kp_idx) {
    __shared__ uint32_t S[NBINS + 8];
    __shared__ uint64_t keys[SORT_CAP];
    __shared__ uint32_t wtot[16], wsfx[16];
    __shared__ uint32_t sThr;
    int b = blockIdx.x;
    int tid = threadIdx.x;
    int wid = tid >> 6, lane = tid & 63;
    const int s0 = b * TASKS_B;

    for (int i = tid; i < NBINS + 8; i += 1024) S[i] = 0u;
    if (tid == 0) sThr = 0u;
    __syncthreads();

    for (int s = s0 + tid; s < s0 + TASKS_B; s += 1024) {
        uint32_t c = counts[s];
        for (uint32_t j = 0; j < c; ++j)
            atomicAdd(&S[(uint32_t)(cand[(size_t)j * NTASK + s] >> 51)], 1u);
    }
    __syncthreads();

    // suffix sums over 4096 bins; thread t owns bins [4t,4t+4)
    uint32_t h0 = S[4*tid], h1 = S[4*tid+1], h2 = S[4*tid+2], h3 = S[4*tid+3];
    uint32_t tot = h0 + h1 + h2 + h3;
    uint32_t x = tot;                       // in-wave inclusive suffix scan
    #pragma unroll
    for (int off = 1; off < 64; off <<= 1) {
        uint32_t v = __shfl_down(x, off);
        if (lane + off < 64) x += v;
    }
    if (lane == 0) wtot[wid] = x;           // wave total
    __syncthreads();
    if (wid == 0) {
        uint32_t v = (lane < 16) ? wtot[lane] : 0u;
        #pragma unroll
        for (int off = 1; off < 16; off <<= 1) {
            uint32_t u = __shfl_down(v, off);
            if (lane + off < 16) v += u;
        }
        if (lane < 16) wsfx[lane] = v;      // inclusive suffix over waves
    }
    __syncthreads();
    {
        uint32_t later = (wid < 15) ? wsfx[wid + 1] : 0u;
        uint32_t sfx4 = (x - tot) + later;  // suffix starting at bin 4(tid+1)
        uint32_t S3 = h3 + sfx4, S2 = h2 + S3, S1 = h1 + S2, S0 = h0 + S1;
        S[4*tid] = S0; S[4*tid+1] = S1; S[4*tid+2] = S2; S[4*tid+3] = S3;
        if (S3 >= KK && sfx4 < KK) sThr = (uint32_t)(4*tid + 3);
        if (S2 >= KK && S3   < KK) sThr = (uint32_t)(4*tid + 2);
        if (S1 >= KK && S2   < KK) sThr = (uint32_t)(4*tid + 1);
        if (S0 >= KK && S1   < KK) sThr = (uint32_t)(4*tid + 0);
    }
    __syncthreads();

    uint32_t thr = sThr;
    uint32_t m = S[thr];
    if (m > SORT_CAP) m = SORT_CAP;

    // counting-scatter (bin-grouped); post-scatter S[i+1] = S_old[i]
    for (int s = s0 + tid; s < s0 + TASKS_B; s += 1024) {
        uint32_t c = counts[s];
        for (uint32_t j = 0; j < c; ++j) {
            uint64_t key = cand[(size_t)j * NTASK + s];
            uint32_t bin = (uint32_t)(key >> 51);
            if (bin >= thr) {
                uint32_t p = atomicAdd(&S[bin + 1], 1u);
                if (p < SORT_CAP) keys[p] = key;
            }
        }
    }
    __syncthreads();

    // rank = segment base + within-bin greater-count; emit
    float* out_kp = out;                      // (B,K,2)
    float* out_sc = out + (size_t)Bb * KK * 2;
    for (uint32_t p = tid; p < m; p += 1024) {
        uint64_t key = keys[p];
        uint32_t bin = (uint32_t)(key >> 51);
        uint32_t base = S[bin + 2];           // = S_old[bin+1]
        uint32_t end  = S[bin + 1];           // = S_old[bin]
        if (end > m) end = m;
        uint32_t rank = base;
        for (uint32_t q = base; q < end; ++q)
            rank += (keys[q] > key) ? 1u : 0u;
        if (rank < KK) {
            uint32_t idx = ~((uint32_t)key);
            uint32_t yy = idx / Ww, xx = idx - yy * Ww;
            size_t o = (size_t)b * KK + rank;
            out_kp[o * 2 + 0] = (float)xx;
            out_kp[o * 2 + 1] = (float)yy;
            out_sc[o] = __uint_as_float((uint32_t)(key >> 32));
            kp_idx[o] = idx;
        }
    }
}

// 4 keypoints per 256-thread block (one per wave); lane c loads channels c, c+64.
__global__ __launch_bounds__(256) void gather_desc(const float* __restrict__ unet,
                                                   const uint32_t* __restrict__ kp_idx,
                                                   float* __restrict__ out_desc) {
    int kp = blockIdx.x * 4 + (threadIdx.x >> 6);
    int lane = threadIdx.x & 63;
    int b = kp >> 11;
    uint32_t idx = kp_idx[kp];
    const float* base = unet + (size_t)b * Cc * HW + idx;
    float v0 = base[(size_t)lane * HW];
    float v1 = base[(size_t)(lane + 64) * HW];
    float s = v0 * v0 + v1 * v1;
    #pragma unroll
    for (int off = 32; off > 0; off >>= 1) s += __shfl_xor(s, off);
    float rn = 1.0f / fmaxf(sqrtf(s), 1e-12f);
    float* o = out_desc + (size_t)kp * DESC;
    o[lane]      = v0 * rn;
    o[lane + 64] = v1 * rn;
}

extern "C" void kernel_launch(void* const* d_in, const int* in_sizes, int n_in,
                              void* d_out, int out_size, void* d_ws, size_t ws_size,
                              hipStream_t stream) {
    const float* unet = (const float*)d_in[0];
    float* out = (float*)d_out;
    uint8_t* ws = (uint8_t*)d_ws;

    uint64_t* cand   = (uint64_t*)(ws);                       // 24*26624*8 = 5,111,808
    uint32_t* counts = (uint32_t*)(ws + 5111808);             // 106,496
    uint32_t* kp_idx = (uint32_t*)(ws + 5218304);             // 32,768

    float* out_desc = out + (size_t)Bb * KK * 2 + (size_t)Bb * KK;

    nms_collect<<<NTASK / 4, 256, 0, stream>>>(unet, cand, counts);
    topk_rank<<<Bb, 1024, 0, stream>>>(cand, counts, out, kp_idx);
    gather_desc<<<Bb * KK / 4, 256, 0, stream>>>(unet, kp_idx, out_desc);
}

// Round 13
// 123.478 us; speedup vs baseline: 4.5291x; 1.0208x over previous
//
#include <hip/hip_runtime.h>
#include <stdint.h>

#define Hh 512
#define Ww 768
#define HW (Hh*Ww)
#define Bb 4
#define Cc 129
#define DESC 128
#define KK 2048
#define NBINS 4096
#define CAP 24                    // max survivors per 60-wide chunk (no-tie bound is 20)
#define CHUNKS 13
#define NTASK (Bb*Hh*CHUNKS)      // 26624 row-chunk tasks
#define TASKS_B (Hh*CHUNKS)       // 6656 per batch
#define SORT_CAP 4096
#define ROWG 4                    // output rows per wave
#define NMS_WAVES (Bb*(Hh/ROWG)*CHUNKS)   // 6656 waves
#define NMS_BLOCKS (NMS_WAVES/4)          // 1664

// Separable 5x5 NMS with 4-row register reuse: one wave loads 8 clamped rows,
// derives 4 vertical 5-windows, horizontal max via shuffles. Atomic-free emit:
// each row-chunk task owns CAP transposed slots cand[j][task]; counts[task]
// plain-stored every call (no zero kernel, poison-safe).
__global__ __launch_bounds__(256) void nms_collect(const float* __restrict__ unet,
                                                   uint64_t* __restrict__ cand,
                                                   uint32_t* __restrict__ counts) {
    int wid = threadIdx.x >> 6;
    int lane = threadIdx.x & 63;
    int w = blockIdx.x * 4 + wid;          // wave task-group id
    int chunk = w % CHUNKS;
    int g = w / CHUNKS;                    // 0..2047 = b*128 + rowgroup
    int b = g >> 7;
    int y0 = (g & 127) * ROWG;
    int x = chunk * 60 + lane - 2;
    int xc = min(max(x, 0), Ww - 1);
    const float* hb = unet + ((size_t)(b * Cc + DESC)) * HW;

    float r[ROWG + 4];
    #pragma unroll
    for (int k = 0; k < ROWG + 4; ++k) {
        int ry = min(max(y0 + k - 2, 0), Hh - 1);
        r[k] = hb[(size_t)ry * Ww + xc];
    }

    bool okx = (lane >= 2) && (lane <= 61) && (x < Ww);
    #pragma unroll
    for (int k = 0; k < ROWG; ++k) {
        float vm = fmaxf(fmaxf(fmaxf(r[k], r[k+1]), fmaxf(r[k+3], r[k+4])), r[k+2]);
        float m1 = fmaxf(__shfl(vm, lane - 1), __shfl(vm, lane + 1));
        float m2 = fmaxf(__shfl(vm, lane - 2), __shfl(vm, lane + 2));
        float hm = fmaxf(vm, fmaxf(m1, m2));
        float v = r[k + 2];
        bool surv = okx && (v > 0.0f) && (v >= hm);
        uint64_t ball = __ballot(surv);
        int task = (b * Hh + y0 + k) * CHUNKS + chunk;
        if (surv) {
            uint32_t p = (uint32_t)__popcll(ball & ((1ull << lane) - 1ull));
            if (p < CAP)
                cand[(size_t)p * NTASK + task] =
                    ((uint64_t)__float_as_uint(v) << 32) | (uint32_t)(~(uint32_t)((y0 + k) * Ww + x));
        }
        if (lane == 0) counts[task] = min((uint32_t)__popcll(ball), (uint32_t)CAP);
    }
}

// Per-batch rank-by-counting top-k. Suffix scan via wave shuffles (3 barriers).
// Emits coords/scores at rank and kp_idx[b*KK+rank] = pixel idx.
__global__ __launch_bounds__(1024) void topk_rank(const uint64_t* __restrict__ cand,
                                                  const uint32_t* __restrict__ counts,
                                                  float* __restrict__ out,
                                                  uint32_t* __restrict__ kp_idx) {
    __shared__ uint32_t S[NBINS + 8];
    __shared__ uint64_t keys[SORT_CAP];
    __shared__ uint32_t wtot[16], wsfx[16];
    __shared__ uint32_t sThr;
    int b = blockIdx.x;
    int tid = threadIdx.x;
    int wid = tid >> 6, lane = tid & 63;
    const int s0 = b * TASKS_B;

    for (int i = tid; i < NBINS + 8; i += 1024) S[i] = 0u;
    if (tid == 0) sThr = 0u;
    __syncthreads();

    for (int s = s0 + tid; s < s0 + TASKS_B; s += 1024) {
        uint32_t c = counts[s];
        for (uint32_t j = 0; j < c; ++j)
            atomicAdd(&S[(uint32_t)(cand[(size_t)j * NTASK + s] >> 51)], 1u);
    }
    __syncthreads();

    // suffix sums over 4096 bins; thread t owns bins [4t,4t+4)
    uint32_t h0 = S[4*tid], h1 = S[4*tid+1], h2 = S[4*tid+2], h3 = S[4*tid+3];
    uint32_t tot = h0 + h1 + h2 + h3;
    uint32_t x = tot;                       // in-wave inclusive suffix scan
    #pragma unroll
    for (int off = 1; off < 64; off <<= 1) {
        uint32_t v = __shfl_down(x, off);
        if (lane + off < 64) x += v;
    }
    if (lane == 0) wtot[wid] = x;
    __syncthreads();
    if (wid == 0) {
        uint32_t v = (lane < 16) ? wtot[lane] : 0u;
        #pragma unroll
        for (int off = 1; off < 16; off <<= 1) {
            uint32_t u = __shfl_down(v, off);
            if (lane + off < 16) v += u;
        }
        if (lane < 16) wsfx[lane] = v;
    }
    __syncthreads();
    {
        uint32_t later = (wid < 15) ? wsfx[wid + 1] : 0u;
        uint32_t sfx4 = (x - tot) + later;
        uint32_t S3 = h3 + sfx4, S2 = h2 + S3, S1 = h1 + S2, S0 = h0 + S1;
        S[4*tid] = S0; S[4*tid+1] = S1; S[4*tid+2] = S2; S[4*tid+3] = S3;
        if (S3 >= KK && sfx4 < KK) sThr = (uint32_t)(4*tid + 3);
        if (S2 >= KK && S3   < KK) sThr = (uint32_t)(4*tid + 2);
        if (S1 >= KK && S2   < KK) sThr = (uint32_t)(4*tid + 1);
        if (S0 >= KK && S1   < KK) sThr = (uint32_t)(4*tid + 0);
    }
    __syncthreads();

    uint32_t thr = sThr;
    uint32_t m = S[thr];
    if (m > SORT_CAP) m = SORT_CAP;

    // counting-scatter (bin-grouped); post-scatter S[i+1] = S_old[i]
    for (int s = s0 + tid; s < s0 + TASKS_B; s += 1024) {
        uint32_t c = counts[s];
        for (uint32_t j = 0; j < c; ++j) {
            uint64_t key = cand[(size_t)j * NTASK + s];
            uint32_t bin = (uint32_t)(key >> 51);
            if (bin >= thr) {
                uint32_t p = atomicAdd(&S[bin + 1], 1u);
                if (p < SORT_CAP) keys[p] = key;
            }
        }
    }
    __syncthreads();

    // rank = segment base + within-bin greater-count; emit
    float* out_kp = out;                      // (B,K,2)
    float* out_sc = out + (size_t)Bb * KK * 2;
    for (uint32_t p = tid; p < m; p += 1024) {
        uint64_t key = keys[p];
        uint32_t bin = (uint32_t)(key >> 51);
        uint32_t base = S[bin + 2];           // = S_old[bin+1]
        uint32_t end  = S[bin + 1];           // = S_old[bin]
        if (end > m) end = m;
        uint32_t rank = base;
        for (uint32_t q = base; q < end; ++q)
            rank += (keys[q] > key) ? 1u : 0u;
        if (rank < KK) {
            uint32_t idx = ~((uint32_t)key);
            uint32_t yy = idx / Ww, xx = idx - yy * Ww;
            size_t o = (size_t)b * KK + rank;
            out_kp[o * 2 + 0] = (float)xx;
            out_kp[o * 2 + 1] = (float)yy;
            out_sc[o] = __uint_as_float((uint32_t)(key >> 32));
            kp_idx[o] = idx;
        }
    }
}

// 8 keypoints per 512-thread block (one per wave); lane c loads channels c, c+64.
__global__ __launch_bounds__(512) void gather_desc(const float* __restrict__ unet,
                                                   const uint32_t* __restrict__ kp_idx,
                                                   float* __restrict__ out_desc) {
    int kp = blockIdx.x * 8 + (threadIdx.x >> 6);
    int lane = threadIdx.x & 63;
    int b = kp >> 11;
    uint32_t idx = kp_idx[kp];
    const float* base = unet + (size_t)b * Cc * HW + idx;
    float v0 = base[(size_t)lane * HW];
    float v1 = base[(size_t)(lane + 64) * HW];
    float s = v0 * v0 + v1 * v1;
    #pragma unroll
    for (int off = 32; off > 0; off >>= 1) s += __shfl_xor(s, off);
    float rn = 1.0f / fmaxf(sqrtf(s), 1e-12f);
    float* o = out_desc + (size_t)kp * DESC;
    o[lane]      = v0 * rn;
    o[lane + 64] = v1 * rn;
}

extern "C" void kernel_launch(void* const* d_in, const int* in_sizes, int n_in,
                              void* d_out, int out_size, void* d_ws, size_t ws_size,
                              hipStream_t stream) {
    const float* unet = (const float*)d_in[0];
    float* out = (float*)d_out;
    uint8_t* ws = (uint8_t*)d_ws;

    uint64_t* cand   = (uint64_t*)(ws);                       // 24*26624*8 = 5,111,808
    uint32_t* counts = (uint32_t*)(ws + 5111808);             // 106,496
    uint32_t* kp_idx = (uint32_t*)(ws + 5218304);             // 32,768

    float* out_desc = out + (size_t)Bb * KK * 2 + (size_t)Bb * KK;

    nms_collect<<<NMS_BLOCKS, 256, 0, stream>>>(unet, cand, counts);
    topk_rank<<<Bb, 1024, 0, stream>>>(cand, counts, out, kp_idx);
    gather_desc<<<Bb * KK / 8, 512, 0, stream>>>(unet, kp_idx, out_desc);
}